// Round 9
// baseline (368.244 us; speedup 1.0000x reference)
//
#include <hip/hip_runtime.h>

#define NS  262144
#define NN  24
#define CI  32
#define HW  32
#define SPB 16                    // samples per tile (24KB f16 LDS per buffer)
#define TPB 8                     // tiles per block -> 128 samples/block

typedef __fp16 fp16x2v __attribute__((ext_vector_type(2)));
typedef _Float16 half2v __attribute__((ext_vector_type(2)));
typedef _Float16 half8 __attribute__((ext_vector_type(8)));
typedef float f32x4 __attribute__((ext_vector_type(4)));
typedef unsigned int u32x4 __attribute__((ext_vector_type(4)));

// f16 fragments of W1^T used as the MFMA *A* operand:
// g_w1f[n][half][lane][i] = W1[n][c=(lane>>4)*8+i][w=half*16+(lane&15)]
__device__ alignas(16) unsigned short g_w1f[NN * 2 * 64 * 8];

__global__ void pack_w1(const float* __restrict__ W1) {
  int idx = blockIdx.x * 256 + threadIdx.x;
  if (idx >= NN * 2 * 64 * 8) return;
  int i    = idx & 7;
  int lane = (idx >> 3) & 63;
  int hf   = (idx >> 9) & 1;
  int n    = idx >> 10;
  int k = (lane >> 4) * 8 + i;
  int w = hf * 16 + (lane & 15);
  _Float16 v = (_Float16)W1[(n * CI + k) * HW + w];
  g_w1f[idx] = __builtin_bit_cast(unsigned short, v);
}

__device__ __forceinline__ unsigned pkrtz(float a, float b) {
#if __has_builtin(__builtin_amdgcn_cvt_pkrtz)
  fp16x2v p = __builtin_amdgcn_cvt_pkrtz(a, b);
  return __builtin_bit_cast(unsigned, p);
#else
  half2v p;
  p[0] = (_Float16)a;
  p[1] = (_Float16)b;
  return __builtin_bit_cast(unsigned, p);
#endif
}

__global__ __launch_bounds__(256, 3) void mlp_mfma(
    const float* __restrict__ h, const int* __restrict__ valid,
    const float* __restrict__ b1, const float* __restrict__ W2,
    const float* __restrict__ b2, float* __restrict__ out) {
  // Double-buffered f16 relu(h) tiles, [n][s][c] + ((s^n)&7)<<4 swizzle
  // (formulas byte-identical to R8, which passed).
  __shared__ alignas(16) unsigned short lds[2][NN * SPB * CI];  // 2x24KB

  const int tid  = threadIdx.x;
  const int lane = tid & 63;
  const int wv   = tid >> 6;
  const int r    = lane & 15;    // B col = sample; A row = hidden w
  const int q    = lane >> 4;    // k-chunk group; C row-group
  const int sB   = blockIdx.x * (SPB * TPB);

  // ---- Resident W1 fragments for this wave's 6 nodes (read ONCE per block)
  half8 Af0[6], Af1[6];
#pragma unroll
  for (int ni = 0; ni < 6; ++ni) {
    const int n = wv * 6 + ni;
    Af0[ni] = __builtin_bit_cast(half8,
        *(const u32x4*)&g_w1f[((n * 2 + 0) * 64 + lane) * 8]);
    Af1[ni] = __builtin_bit_cast(half8,
        *(const u32x4*)&g_w1f[((n * 2 + 1) * 64 + lane) * 8]);
  }

  f32x4 ra[6], rb[6];            // in-flight stage registers (one tile)

  // ---- Prologue: stage tile 0 into buf 0
#pragma unroll
  for (int rd = 0; rd < 6; ++rd) {
    const float* hp = h + (size_t)sB * (NN * CI) + (size_t)(rd * 256 + tid) * 8;
    ra[rd] = *(const f32x4*)hp;
    rb[rd] = *(const f32x4*)(hp + 4);
  }
#pragma unroll
  for (int rd = 0; rd < 6; ++rd) {
    const int c32 = rd * 256 + tid;
    const int row = c32 >> 2, q2 = c32 & 3;
    const int sl  = row / NN, n = row - sl * NN;
    u32x4 u;
    u[0] = pkrtz(fmaxf(ra[rd][0], 0.f), fmaxf(ra[rd][1], 0.f));
    u[1] = pkrtz(fmaxf(ra[rd][2], 0.f), fmaxf(ra[rd][3], 0.f));
    u[2] = pkrtz(fmaxf(rb[rd][0], 0.f), fmaxf(rb[rd][1], 0.f));
    u[3] = pkrtz(fmaxf(rb[rd][2], 0.f), fmaxf(rb[rd][3], 0.f));
    int byte = n * (SPB * CI * 2) + sl * (CI * 2) + q2 * 16;
    byte ^= ((sl ^ n) & 7) << 4;
    *(u32x4*)((char*)lds[0] + byte) = u;
  }
  __syncthreads();

  for (int t = 0; t < TPB; ++t) {
    const int p = t & 1;

    // Issue NEXT tile's global loads FIRST (hide HBM under this tile's MFMA)
    if (t + 1 < TPB) {
      const float* gbt = h + (size_t)(sB + (t + 1) * SPB) * (NN * CI);
#pragma unroll
      for (int rd = 0; rd < 6; ++rd) {
        const float* hp = gbt + (size_t)(rd * 256 + tid) * 8;
        ra[rd] = *(const f32x4*)hp;
        rb[rd] = *(const f32x4*)(hp + 4);
      }
    }

    // Compute current tile from lds[p]
    const int sBt = sB + t * SPB;
#pragma unroll
    for (int ni = 0; ni < 6; ++ni) {
      const int n = wv * 6 + ni;
      f32x4 b1a = *(const f32x4*)&b1[n * HW + q * 4];
      f32x4 b1b = *(const f32x4*)&b1[n * HW + 16 + q * 4];
      f32x4 w2a = *(const f32x4*)&W2[n * HW + q * 4];
      f32x4 w2b = *(const f32x4*)&W2[n * HW + 16 + q * 4];
      float b2n = b2[n];

      int byte = n * (SPB * CI * 2) + r * (CI * 2) + q * 16;
      byte ^= ((r ^ n) & 7) << 4;
      half8 Hf = *(const half8*)((const char*)lds[p] + byte);

      f32x4 c0 = {b1a[0], b1a[1], b1a[2], b1a[3]};
      f32x4 c1 = {b1b[0], b1b[1], b1b[2], b1b[3]};
      c0 = __builtin_amdgcn_mfma_f32_16x16x32_f16(Af0[ni], Hf, c0, 0, 0, 0);
      c1 = __builtin_amdgcn_mfma_f32_16x16x32_f16(Af1[ni], Hf, c1, 0, 0, 0);

      float pacc = 0.f;
#pragma unroll
      for (int i = 0; i < 4; ++i) {
        pacc = fmaf(fmaxf(c0[i], 0.f), w2a[i], pacc);
        pacc = fmaf(fmaxf(c1[i], 0.f), w2b[i], pacc);
      }
      pacc += __shfl_xor(pacc, 16);
      pacc += __shfl_xor(pacc, 32);

      if (lane < 16) {
        const int srow = sBt + r;
        const int vv = valid[srow * NN + n];
        out[(size_t)srow * NN + n] = vv ? (pacc + b2n) : 0.0f;
      }
    }

    // Write-late: drain the in-flight loads into the OTHER buffer
    if (t + 1 < TPB) {
#pragma unroll
      for (int rd = 0; rd < 6; ++rd) {
        const int c32 = rd * 256 + tid;
        const int row = c32 >> 2, q2 = c32 & 3;
        const int sl  = row / NN, n = row - sl * NN;
        u32x4 u;
        u[0] = pkrtz(fmaxf(ra[rd][0], 0.f), fmaxf(ra[rd][1], 0.f));
        u[1] = pkrtz(fmaxf(ra[rd][2], 0.f), fmaxf(ra[rd][3], 0.f));
        u[2] = pkrtz(fmaxf(rb[rd][0], 0.f), fmaxf(rb[rd][1], 0.f));
        u[3] = pkrtz(fmaxf(rb[rd][2], 0.f), fmaxf(rb[rd][3], 0.f));
        int byte = n * (SPB * CI * 2) + sl * (CI * 2) + q2 * 16;
        byte ^= ((sl ^ n) & 7) << 4;
        *(u32x4*)((char*)lds[p ^ 1] + byte) = u;
      }
    }
    __syncthreads();
  }
}

extern "C" void kernel_launch(void* const* d_in, const int* in_sizes, int n_in,
                              void* d_out, int out_size, void* d_ws, size_t ws_size,
                              hipStream_t stream) {
  const float* h     = (const float*)d_in[0];
  const int*   valid = (const int*)d_in[1];
  const float* W1    = (const float*)d_in[2];
  const float* b1    = (const float*)d_in[3];
  const float* W2    = (const float*)d_in[4];
  const float* b2    = (const float*)d_in[5];
  float* out = (float*)d_out;

  hipLaunchKernelGGL(pack_w1, dim3((NN * 2 * 64 * 8 + 255) / 256), dim3(256),
                     0, stream, W1);
  hipLaunchKernelGGL(mlp_mfma, dim3(NS / (SPB * TPB)), dim3(256), 0, stream,
                     h, valid, b1, W2, b2, out);
}

// Round 11
// 295.184 us; speedup vs baseline: 1.2475x; 1.2475x over previous
//
#include <hip/hip_runtime.h>

#define NS  262144
#define NN  24
#define CI  32
#define HW  32

typedef __fp16 fp16x2v __attribute__((ext_vector_type(2)));
typedef _Float16 half2v __attribute__((ext_vector_type(2)));
typedef _Float16 half8 __attribute__((ext_vector_type(8)));
typedef float f32x4 __attribute__((ext_vector_type(4)));
typedef unsigned int u32x4 __attribute__((ext_vector_type(4)));

// f16 fragments of W1^T used as the MFMA *A* operand (verified R2-R9):
// g_w1f[n][half][lane][i] = W1[n][c=(lane>>4)*8+i][w=half*16+(lane&15)]
__device__ alignas(16) unsigned short g_w1f[NN * 2 * 64 * 8];

__global__ void pack_w1(const float* __restrict__ W1) {
  int idx = blockIdx.x * 256 + threadIdx.x;
  if (idx >= NN * 2 * 64 * 8) return;
  int i    = idx & 7;
  int lane = (idx >> 3) & 63;
  int hf   = (idx >> 9) & 1;
  int n    = idx >> 10;
  int k = (lane >> 4) * 8 + i;
  int w = hf * 16 + (lane & 15);
  _Float16 v = (_Float16)W1[(n * CI + k) * HW + w];
  g_w1f[idx] = __builtin_bit_cast(unsigned short, v);
}

__device__ __forceinline__ unsigned pkrtz(float a, float b) {
#if __has_builtin(__builtin_amdgcn_cvt_pkrtz)
  fp16x2v p = __builtin_amdgcn_cvt_pkrtz(a, b);
  return __builtin_bit_cast(unsigned, p);
#else
  half2v p;
  p[0] = (_Float16)a;
  p[1] = (_Float16)b;
  return __builtin_bit_cast(unsigned, p);
#endif
}

// Dense-direct: NO h staging, NO valid-skip, NO barrier in the main loop.
__global__ __launch_bounds__(256, 4) void mlp_mfma(
    const float* __restrict__ h, const int* __restrict__ valid,
    const float* __restrict__ b1, const float* __restrict__ W2,
    const float* __restrict__ b2, float* __restrict__ out) {
  __shared__ float sb1[NN * HW];   // 3KB
  __shared__ float sw2[NN * HW];   // 3KB
  __shared__ float sb2[NN];        // 96B

  const int tid = threadIdx.x;
  // Table staging (R10 bugfix: each t4<768 thread loads BOTH quads — the
  // old else-if left sw2[256..768) uninitialized).
  {
    const int t4 = tid * 4;
    if (t4 < NN * HW) {
      *(f32x4*)&sb1[t4] = *(const f32x4*)&b1[t4];
      *(f32x4*)&sw2[t4] = *(const f32x4*)&W2[t4];
    }
    if (tid < NN) sb2[tid] = b2[tid];
  }
  __syncthreads();

  const int lane = tid & 63;
  const int wv   = tid >> 6;
  const int r    = lane & 15;     // B col = sample; A row = hidden w
  const int q    = lane >> 4;     // k-chunk group; C row-group
  const int s0   = blockIdx.x * 64 + wv * 16;
  const int srow = s0 + r;

  const float* __restrict__ hbase = h + (size_t)srow * (NN * CI) + q * 8;

#pragma unroll 4
  for (int n = 0; n < NN; ++n) {
    // Independent loads every iteration -> deep VMEM pipelining.
    const int vld = valid[srow * NN + n];
    const float* hp = hbase + n * CI;
    f32x4 av0 = *(const f32x4*)hp;
    f32x4 av1 = *(const f32x4*)(hp + 4);

    half8 Af0 = __builtin_bit_cast(half8,
        *(const u32x4*)&g_w1f[((n * 2 + 0) * 64 + lane) * 8]);
    half8 Af1 = __builtin_bit_cast(half8,
        *(const u32x4*)&g_w1f[((n * 2 + 1) * 64 + lane) * 8]);
    f32x4 b1a = *(const f32x4*)&sb1[n * HW + q * 4];
    f32x4 b1b = *(const f32x4*)&sb1[n * HW + 16 + q * 4];
    f32x4 w2a = *(const f32x4*)&sw2[n * HW + q * 4];
    f32x4 w2b = *(const f32x4*)&sw2[n * HW + 16 + q * 4];
    const float b2n = sb2[n];

    u32x4 uu;
    uu[0] = pkrtz(fmaxf(av0[0], 0.f), fmaxf(av0[1], 0.f));
    uu[1] = pkrtz(fmaxf(av0[2], 0.f), fmaxf(av0[3], 0.f));
    uu[2] = pkrtz(fmaxf(av1[0], 0.f), fmaxf(av1[1], 0.f));
    uu[3] = pkrtz(fmaxf(av1[2], 0.f), fmaxf(av1[3], 0.f));
    half8 Hf = __builtin_bit_cast(half8, uu);

    f32x4 c0 = {b1a[0], b1a[1], b1a[2], b1a[3]};
    f32x4 c1 = {b1b[0], b1b[1], b1b[2], b1b[3]};
    c0 = __builtin_amdgcn_mfma_f32_16x16x32_f16(Af0, Hf, c0, 0, 0, 0);
    c1 = __builtin_amdgcn_mfma_f32_16x16x32_f16(Af1, Hf, c1, 0, 0, 0);

    float p = 0.f;
#pragma unroll
    for (int i = 0; i < 4; ++i) {
      p = fmaf(fmaxf(c0[i], 0.f), w2a[i], p);
      p = fmaf(fmaxf(c1[i], 0.f), w2b[i], p);
    }
    p += __shfl_xor(p, 16);
    p += __shfl_xor(p, 32);

    if (lane < 16)
      out[(size_t)srow * NN + n] = vld ? (p + b2n) : 0.0f;
  }
}

extern "C" void kernel_launch(void* const* d_in, const int* in_sizes, int n_in,
                              void* d_out, int out_size, void* d_ws, size_t ws_size,
                              hipStream_t stream) {
  const float* h     = (const float*)d_in[0];
  const int*   valid = (const int*)d_in[1];
  const float* W1    = (const float*)d_in[2];
  const float* b1    = (const float*)d_in[3];
  const float* W2    = (const float*)d_in[4];
  const float* b2    = (const float*)d_in[5];
  float* out = (float*)d_out;

  hipLaunchKernelGGL(pack_w1, dim3((NN * 2 * 64 * 8 + 255) / 256), dim3(256),
                     0, stream, W1);
  hipLaunchKernelGGL(mlp_mfma, dim3(NS / 64), dim3(256), 0, stream,
                     h, valid, b1, W2, b2, out);
}

// Round 12
// 292.973 us; speedup vs baseline: 1.2569x; 1.0075x over previous
//
#include <hip/hip_runtime.h>

#define NS   262144
#define NN   24
#define CI   32
#define HW   32
#define SPB  16                    // samples per tile
#define NTILES (NS / SPB)          // 16384
#define NBLK 256                   // persistent: 1 block per CU
#define TPB  (NTILES / NBLK)       // 64 tiles per block (3MB contiguous h)

typedef __fp16 fp16x2v __attribute__((ext_vector_type(2)));
typedef _Float16 half2v __attribute__((ext_vector_type(2)));
typedef _Float16 half8 __attribute__((ext_vector_type(8)));
typedef float f32x4 __attribute__((ext_vector_type(4)));
typedef unsigned int u32x4 __attribute__((ext_vector_type(4)));

// f16 fragments of W1^T used as the MFMA *A* operand (verified R2-R11):
// g_w1f[n][half][lane][i] = W1[n][c=(lane>>4)*8+i][w=half*16+(lane&15)]
__device__ alignas(16) unsigned short g_w1f[NN * 2 * 64 * 8];

__global__ void pack_w1(const float* __restrict__ W1) {
  int idx = blockIdx.x * 256 + threadIdx.x;
  if (idx >= NN * 2 * 64 * 8) return;
  int i    = idx & 7;
  int lane = (idx >> 3) & 63;
  int hf   = (idx >> 9) & 1;
  int n    = idx >> 10;
  int k = (lane >> 4) * 8 + i;
  int w = hf * 16 + (lane & 15);
  _Float16 v = (_Float16)W1[(n * CI + k) * HW + w];
  g_w1f[idx] = __builtin_bit_cast(unsigned short, v);
}

__device__ __forceinline__ unsigned pkrtz(float a, float b) {
  fp16x2v p = __builtin_amdgcn_cvt_pkrtz(a, b);
  return __builtin_bit_cast(unsigned, p);
}

__device__ __forceinline__ void gload16(const float* g, float* l) {
  __builtin_amdgcn_global_load_lds(
      (const __attribute__((address_space(1))) void*)g,
      (__attribute__((address_space(3))) void*)l, 16, 0, 0);
}

__global__ __launch_bounds__(256) void mlp_mfma(
    const float* __restrict__ h, const int* __restrict__ valid,
    const float* __restrict__ b1, const float* __restrict__ W2,
    const float* __restrict__ b2, float* __restrict__ out) {
  // Double-buffered raw-f32 h tiles + tables: 2x48KB + 6KB = 102KB -> 1 blk/CU
  __shared__ alignas(16) float buf[2][SPB * NN * CI];
  __shared__ float sb1[NN * HW], sw2[NN * HW], sb2v[NN];

  const int tid  = threadIdx.x;
  const int lane = tid & 63;
  const int wv   = tid >> 6;
  const int r    = lane & 15;    // B col = sample; A row = hidden w
  const int q    = lane >> 4;    // k-chunk group; C row-group

  {  // tables (each t4<768 thread loads BOTH quads — R10 lesson)
    const int t4 = tid * 4;
    if (t4 < NN * HW) {
      *(f32x4*)&sb1[t4] = *(const f32x4*)&b1[t4];
      *(f32x4*)&sw2[t4] = *(const f32x4*)&W2[t4];
    }
    if (tid < NN) sb2v[tid] = b2[tid];
  }

  // Register-resident W1 fragments for this wave's 6 nodes (once per block)
  half8 Af0[6], Af1[6];
#pragma unroll
  for (int ni = 0; ni < 6; ++ni) {
    const int n = wv * 6 + ni;
    Af0[ni] = __builtin_bit_cast(half8,
        *(const u32x4*)&g_w1f[((n * 2 + 0) * 64 + lane) * 8]);
    Af1[ni] = __builtin_bit_cast(half8,
        *(const u32x4*)&g_w1f[((n * 2 + 1) * 64 + lane) * 8]);
  }

  const int lane16 = lane * 16;      // byte offset of this lane's DMA slot
  const int tile0  = blockIdx.x * TPB;

  // DMA-stage one 48KB tile: wave wv covers sample-rows [wv*4, wv*4+4),
  // 3 x 1KB instrs per row. Global source is PRE-SWIZZLED by
  // (lane16 ^ ((s&7)<<4)) so the linear LDS ends up XOR-swizzled
  // (involution verified: s-bits untouched by the XOR).
#define STAGE(tile, dst)                                                     \
  do {                                                                       \
    const float* gt = h + (size_t)(tile) * (SPB * NN * CI);                  \
    _Pragma("unroll") for (int k2 = 0; k2 < 12; ++k2) {                      \
      const int s  = wv * 4 + (k2 / 3);                                      \
      const int pp = k2 % 3;                                                 \
      const int ub = s * 768 + pp * 256; /* float idx of 1KB segment */      \
      gload16(gt + ub + ((lane16 ^ ((s & 7) << 4)) >> 2), (dst) + ub);       \
    }                                                                        \
  } while (0)

  STAGE(tile0, buf[0]);
  __syncthreads();   // drains vmcnt(0) -> tile0 resident

  // Per-thread swizzled ds_read bases (node offset folded in as immediate)
  const int swz = (r & 7) << 4;
  const int aA  = (((r * 3072 + q * 32) ^ swz) + wv * 768);  // + ni*128 imm
  const int aB  = aA ^ 16;

  for (int t = 0; t < TPB; ++t) {
    const char* cb = (const char*)buf[t & 1];

    if (t + 1 < TPB) STAGE(tile0 + t + 1, buf[(t + 1) & 1]);  // DMA overlaps

    const int srow = (tile0 + t) * SPB + r;

#pragma unroll
    for (int ni = 0; ni < 6; ++ni) {
      const int n = wv * 6 + ni;
      f32x4 d0 = *(const f32x4*)(cb + aA + ni * 128);
      f32x4 d1 = *(const f32x4*)(cb + aB + ni * 128);

      int vld = 0;
      if (lane < 16) vld = valid[srow * NN + n];   // gates only the store

      u32x4 uu;
      uu[0] = pkrtz(fmaxf(d0[0], 0.f), fmaxf(d0[1], 0.f));
      uu[1] = pkrtz(fmaxf(d0[2], 0.f), fmaxf(d0[3], 0.f));
      uu[2] = pkrtz(fmaxf(d1[0], 0.f), fmaxf(d1[1], 0.f));
      uu[3] = pkrtz(fmaxf(d1[2], 0.f), fmaxf(d1[3], 0.f));
      half8 Hf = __builtin_bit_cast(half8, uu);

      f32x4 b1a = *(const f32x4*)&sb1[n * HW + q * 4];
      f32x4 b1b = *(const f32x4*)&sb1[n * HW + 16 + q * 4];
      f32x4 w2a = *(const f32x4*)&sw2[n * HW + q * 4];
      f32x4 w2b = *(const f32x4*)&sw2[n * HW + 16 + q * 4];

      f32x4 c0 = {b1a[0], b1a[1], b1a[2], b1a[3]};
      f32x4 c1 = {b1b[0], b1b[1], b1b[2], b1b[3]};
      c0 = __builtin_amdgcn_mfma_f32_16x16x32_f16(Af0[ni], Hf, c0, 0, 0, 0);
      c1 = __builtin_amdgcn_mfma_f32_16x16x32_f16(Af1[ni], Hf, c1, 0, 0, 0);

      float p = 0.f;
#pragma unroll
      for (int i = 0; i < 4; ++i) {
        p = fmaf(fmaxf(c0[i], 0.f), w2a[i], p);
        p = fmaf(fmaxf(c1[i], 0.f), w2b[i], p);
      }
      p += __shfl_xor(p, 16);
      p += __shfl_xor(p, 32);

      if (lane < 16)
        out[(size_t)srow * NN + n] = vld ? (p + sb2v[n]) : 0.0f;
    }

    __syncthreads();   // waves done reading buf[t&1]; also drains stage(t+1)
  }
#undef STAGE
}

extern "C" void kernel_launch(void* const* d_in, const int* in_sizes, int n_in,
                              void* d_out, int out_size, void* d_ws, size_t ws_size,
                              hipStream_t stream) {
  const float* h     = (const float*)d_in[0];
  const int*   valid = (const int*)d_in[1];
  const float* W1    = (const float*)d_in[2];
  const float* b1    = (const float*)d_in[3];
  const float* W2    = (const float*)d_in[4];
  const float* b2    = (const float*)d_in[5];
  float* out = (float*)d_out;

  hipLaunchKernelGGL(pack_w1, dim3((NN * 2 * 64 * 8 + 255) / 256), dim3(256),
                     0, stream, W1);
  hipLaunchKernelGGL(mlp_mfma, dim3(NBLK), dim3(256), 0, stream,
                     h, valid, b1, W2, b2, out);
}

// Round 13
// 217.618 us; speedup vs baseline: 1.6922x; 1.3463x over previous
//
#include <hip/hip_runtime.h>

#define NS   262144
#define NN   24
#define CI   32
#define HW   32
#define SPB  16                    // samples per tile (48KB f32)
#define NTILES (NS / SPB)          // 16384
#define NBLK 256                   // persistent: 1 block per CU
#define TPB  (NTILES / NBLK)       // 64 tiles per block

typedef __fp16 fp16x2v __attribute__((ext_vector_type(2)));
typedef _Float16 half8 __attribute__((ext_vector_type(8)));
typedef float f32x4 __attribute__((ext_vector_type(4)));
typedef unsigned int u32x4 __attribute__((ext_vector_type(4)));

// f16 fragments of W1^T used as the MFMA *A* operand (verified R2-R12):
// g_w1f[n][half][lane][i] = W1[n][c=(lane>>4)*8+i][w=half*16+(lane&15)]
__device__ alignas(16) unsigned short g_w1f[NN * 2 * 64 * 8];

__global__ void pack_w1(const float* __restrict__ W1) {
  int idx = blockIdx.x * 256 + threadIdx.x;
  if (idx >= NN * 2 * 64 * 8) return;
  int i    = idx & 7;
  int lane = (idx >> 3) & 63;
  int hf   = (idx >> 9) & 1;
  int n    = idx >> 10;
  int k = (lane >> 4) * 8 + i;
  int w = hf * 16 + (lane & 15);
  _Float16 v = (_Float16)W1[(n * CI + k) * HW + w];
  g_w1f[idx] = __builtin_bit_cast(unsigned short, v);
}

__device__ __forceinline__ unsigned pkrtz(float a, float b) {
  fp16x2v p = __builtin_amdgcn_cvt_pkrtz(a, b);
  return __builtin_bit_cast(unsigned, p);
}

__device__ __forceinline__ void gload16(const float* g, float* l) {
  __builtin_amdgcn_global_load_lds(
      (const __attribute__((address_space(1))) void*)g,
      (__attribute__((address_space(3))) void*)l, 16, 0, 0);
}

// 512 threads = 8 waves -> 2 waves/SIMD (R12 ran 1 wave/SIMD: no hiding).
__global__ __launch_bounds__(512, 2) void mlp_mfma(
    const float* __restrict__ h, const int* __restrict__ valid,
    const float* __restrict__ b1, const float* __restrict__ W2,
    const float* __restrict__ b2, float* __restrict__ out) {
  __shared__ alignas(16) float buf[2][SPB * NN * CI];   // 2 x 48KB raw f32
  __shared__ float sb1[NN * HW], sw2[NN * HW], sb2v[NN];

  const int tid  = threadIdx.x;
  const int lane = tid & 63;
  const int wv   = tid >> 6;     // 0..7
  const int r    = lane & 15;    // B col = sample; A row = hidden w
  const int q    = lane >> 4;    // k-chunk group; C row-group

  {  // tables (threads with t4<768 load BOTH quads — R10 lesson)
    const int t4 = tid * 4;
    if (t4 < NN * HW) {
      *(f32x4*)&sb1[t4] = *(const f32x4*)&b1[t4];
      *(f32x4*)&sw2[t4] = *(const f32x4*)&W2[t4];
    }
    if (tid < NN) sb2v[tid] = b2[tid];
  }

  // Register-resident W1 fragments: this wave's 3 nodes
  half8 Af0[3], Af1[3];
#pragma unroll
  for (int ni = 0; ni < 3; ++ni) {
    const int n = wv * 3 + ni;
    Af0[ni] = __builtin_bit_cast(half8,
        *(const u32x4*)&g_w1f[((n * 2 + 0) * 64 + lane) * 8]);
    Af1[ni] = __builtin_bit_cast(half8,
        *(const u32x4*)&g_w1f[((n * 2 + 1) * 64 + lane) * 8]);
  }

  const int tile0 = blockIdx.x * TPB;

  // Stage one 48KB tile: 6 rounds x 512 threads x 16B. Run k=rd*8+wv covers
  // chunks [64k,64k+64) — always within one row-third (192=3*64), so the
  // row s=k/3 is wave-uniform and LDS dest = base + lane*16 (DMA-legal).
  // Global source pre-swizzled by ^((s&7)<<4) so reads swizzle-match.
#define STAGE(tile, dst)                                                      \
  do {                                                                        \
    const float* gt = h + (size_t)(tile) * (SPB * NN * CI);                   \
    _Pragma("unroll") for (int rd = 0; rd < 6; ++rd) {                        \
      const int k2 = rd * 8 + wv;                                             \
      const int s  = k2 / 3, third = k2 % 3;                                  \
      const int dstf = (k2 * 64 + lane) * 4;  /* linear float idx */          \
      const int srcb = ((third * 64 + lane) * 16) ^ ((s & 7) << 4);           \
      gload16(gt + s * 768 + (srcb >> 2), (dst) + dstf);                      \
    }                                                                         \
  } while (0)

  STAGE(tile0, buf[0]);
  __syncthreads();

  // ds_read base: row r, swizzled chunk bits; +n*128 immediate per node
  const int aA = r * 3072 + ((q * 32) ^ ((r & 7) << 4));
  const int aB = aA ^ 16;

  for (int t = 0; t < TPB; ++t) {
    const char* cb = (const char*)buf[t & 1];

    if (t + 1 < TPB) STAGE(tile0 + t + 1, buf[(t + 1) & 1]);

    const int srow = (tile0 + t) * SPB + r;

#pragma unroll
    for (int ni = 0; ni < 3; ++ni) {
      const int n = wv * 3 + ni;
      f32x4 d0 = *(const f32x4*)(cb + aA + n * 128);
      f32x4 d1 = *(const f32x4*)(cb + aB + n * 128);

      int vld = 0;
      if (lane < 16) vld = valid[srow * NN + n];

      u32x4 uu;
      uu[0] = pkrtz(fmaxf(d0[0], 0.f), fmaxf(d0[1], 0.f));
      uu[1] = pkrtz(fmaxf(d0[2], 0.f), fmaxf(d0[3], 0.f));
      uu[2] = pkrtz(fmaxf(d1[0], 0.f), fmaxf(d1[1], 0.f));
      uu[3] = pkrtz(fmaxf(d1[2], 0.f), fmaxf(d1[3], 0.f));
      half8 Hf = __builtin_bit_cast(half8, uu);

      f32x4 b1a = *(const f32x4*)&sb1[n * HW + q * 4];
      f32x4 b1b = *(const f32x4*)&sb1[n * HW + 16 + q * 4];
      f32x4 w2a = *(const f32x4*)&sw2[n * HW + q * 4];
      f32x4 w2b = *(const f32x4*)&sw2[n * HW + 16 + q * 4];

      f32x4 c0 = {b1a[0], b1a[1], b1a[2], b1a[3]};
      f32x4 c1 = {b1b[0], b1b[1], b1b[2], b1b[3]};
      c0 = __builtin_amdgcn_mfma_f32_16x16x32_f16(Af0[ni], Hf, c0, 0, 0, 0);
      c1 = __builtin_amdgcn_mfma_f32_16x16x32_f16(Af1[ni], Hf, c1, 0, 0, 0);

      float p = 0.f;
#pragma unroll
      for (int i = 0; i < 4; ++i) {
        p = fmaf(fmaxf(c0[i], 0.f), w2a[i], p);
        p = fmaf(fmaxf(c1[i], 0.f), w2b[i], p);
      }
      p += __shfl_xor(p, 16);
      p += __shfl_xor(p, 32);

      if (lane < 16)
        out[(size_t)srow * NN + n] = vld ? (p + sb2v[n]) : 0.0f;
    }

    __syncthreads();   // all waves done with buf[t&1]; each drained its stage
  }
#undef STAGE
}

extern "C" void kernel_launch(void* const* d_in, const int* in_sizes, int n_in,
                              void* d_out, int out_size, void* d_ws, size_t ws_size,
                              hipStream_t stream) {
  const float* h     = (const float*)d_in[0];
  const int*   valid = (const int*)d_in[1];
  const float* W1    = (const float*)d_in[2];
  const float* b1    = (const float*)d_in[3];
  const float* W2    = (const float*)d_in[4];
  const float* b2    = (const float*)d_in[5];
  float* out = (float*)d_out;

  hipLaunchKernelGGL(pack_w1, dim3((NN * 2 * 64 * 8 + 255) / 256), dim3(256),
                     0, stream, W1);
  hipLaunchKernelGGL(mlp_mfma, dim3(NBLK), dim3(512), 0, stream,
                     h, valid, b1, W2, b2, out);
}

// Round 14
// 212.319 us; speedup vs baseline: 1.7344x; 1.0250x over previous
//
#include <hip/hip_runtime.h>

#define NS   262144
#define NN   24
#define CI   32
#define HW   32
#define SPB  16                    // samples per tile (48KB f32)
#define NTILES (NS / SPB)          // 16384
#define NBLK 256                   // persistent: 1 block per CU
#define TPB  (NTILES / NBLK)       // 64 tiles per block

typedef __fp16 fp16x2v __attribute__((ext_vector_type(2)));
typedef _Float16 half8 __attribute__((ext_vector_type(8)));
typedef float f32x4 __attribute__((ext_vector_type(4)));
typedef unsigned int u32x4 __attribute__((ext_vector_type(4)));

// f16 fragments of W1^T used as the MFMA *A* operand (verified R2-R13):
// g_w1f[n][half][lane][i] = W1[n][c=(lane>>4)*8+i][w=half*16+(lane&15)]
__device__ alignas(16) unsigned short g_w1f[NN * 2 * 64 * 8];

__global__ void pack_w1(const float* __restrict__ W1) {
  int idx = blockIdx.x * 256 + threadIdx.x;
  if (idx >= NN * 2 * 64 * 8) return;
  int i    = idx & 7;
  int lane = (idx >> 3) & 63;
  int hf   = (idx >> 9) & 1;
  int n    = idx >> 10;
  int k = (lane >> 4) * 8 + i;
  int w = hf * 16 + (lane & 15);
  _Float16 v = (_Float16)W1[(n * CI + k) * HW + w];
  g_w1f[idx] = __builtin_bit_cast(unsigned short, v);
}

__device__ __forceinline__ unsigned pkrtz(float a, float b) {
  fp16x2v p = __builtin_amdgcn_cvt_pkrtz(a, b);
  return __builtin_bit_cast(unsigned, p);
}

__device__ __forceinline__ void gload16(const float* g, float* l) {
  __builtin_amdgcn_global_load_lds(
      (const __attribute__((address_space(1))) void*)g,
      (__attribute__((address_space(3))) void*)l, 16, 0, 0);
}

__global__ __launch_bounds__(512, 2) void mlp_mfma(
    const float* __restrict__ h, const int* __restrict__ valid,
    const float* __restrict__ b1, const float* __restrict__ W2,
    const float* __restrict__ b2, float* __restrict__ out) {
  // 3-deep pipeline: loads for tile t+1 stay in flight ACROSS the barrier
  // (counted vmcnt, never drained to 0 in the loop) — T3/T4.
  __shared__ alignas(16) float buf[3][SPB * NN * CI];   // 3 x 48KB
  __shared__ float sb1[NN * HW], sw2[NN * HW], sb2v[NN];

  const int tid  = threadIdx.x;
  const int lane = tid & 63;
  const int wv   = tid >> 6;     // 0..7
  const int r    = lane & 15;    // B col = sample; A row = hidden w
  const int q    = lane >> 4;    // k-chunk group; C row-group

  {  // tables (threads with t4<768 load BOTH quads — R10 lesson)
    const int t4 = tid * 4;
    if (t4 < NN * HW) {
      *(f32x4*)&sb1[t4] = *(const f32x4*)&b1[t4];
      *(f32x4*)&sw2[t4] = *(const f32x4*)&W2[t4];
    }
    if (tid < NN) sb2v[tid] = b2[tid];
  }

  // Register-resident W1 fragments: this wave's 3 nodes
  half8 Af0[3], Af1[3];
#pragma unroll
  for (int ni = 0; ni < 3; ++ni) {
    const int n = wv * 3 + ni;
    Af0[ni] = __builtin_bit_cast(half8,
        *(const u32x4*)&g_w1f[((n * 2 + 0) * 64 + lane) * 8]);
    Af1[ni] = __builtin_bit_cast(half8,
        *(const u32x4*)&g_w1f[((n * 2 + 1) * 64 + lane) * 8]);
  }

  const int tile0 = blockIdx.x * TPB;

  // Stage one 48KB tile (identical maps to R13, which refchecked OK).
#define STAGE(tile, dst)                                                      \
  do {                                                                        \
    const float* gt = h + (size_t)(tile) * (SPB * NN * CI);                   \
    _Pragma("unroll") for (int rd = 0; rd < 6; ++rd) {                        \
      const int k2 = rd * 8 + wv;                                             \
      const int s  = k2 / 3, third = k2 % 3;                                  \
      const int dstf = (k2 * 64 + lane) * 4;                                  \
      const int srcb = ((third * 64 + lane) * 16) ^ ((s & 7) << 4);           \
      gload16(gt + s * 768 + (srcb >> 2), (dst) + dstf);                      \
    }                                                                         \
  } while (0)

  // ds_read base: row r, swizzled chunk bits; +n*128 per node
  const int aA = r * 3072 + ((q * 32) ^ ((r & 7) << 4));
  const int aB = aA ^ 16;

#define COMPUTE(t, src)                                                       \
  do {                                                                        \
    const char* cb = (const char*)(src);                                      \
    const int srow = (tile0 + (t)) * SPB + r;                                 \
    _Pragma("unroll") for (int ni = 0; ni < 3; ++ni) {                        \
      const int n = wv * 3 + ni;                                              \
      f32x4 d0 = *(const f32x4*)(cb + aA + n * 128);                          \
      f32x4 d1 = *(const f32x4*)(cb + aB + n * 128);                          \
      const int vld = valid[srow * NN + n];                                   \
      u32x4 uu;                                                               \
      uu[0] = pkrtz(fmaxf(d0[0], 0.f), fmaxf(d0[1], 0.f));                    \
      uu[1] = pkrtz(fmaxf(d0[2], 0.f), fmaxf(d0[3], 0.f));                    \
      uu[2] = pkrtz(fmaxf(d1[0], 0.f), fmaxf(d1[1], 0.f));                    \
      uu[3] = pkrtz(fmaxf(d1[2], 0.f), fmaxf(d1[3], 0.f));                    \
      half8 Hf = __builtin_bit_cast(half8, uu);                               \
      f32x4 b1a = *(const f32x4*)&sb1[n * HW + q * 4];                        \
      f32x4 b1b = *(const f32x4*)&sb1[n * HW + 16 + q * 4];                   \
      f32x4 w2a = *(const f32x4*)&sw2[n * HW + q * 4];                        \
      f32x4 w2b = *(const f32x4*)&sw2[n * HW + 16 + q * 4];                   \
      f32x4 c0 = {b1a[0], b1a[1], b1a[2], b1a[3]};                            \
      f32x4 c1 = {b1b[0], b1b[1], b1b[2], b1b[3]};                            \
      c0 = __builtin_amdgcn_mfma_f32_16x16x32_f16(Af0[ni], Hf, c0, 0, 0, 0);  \
      c1 = __builtin_amdgcn_mfma_f32_16x16x32_f16(Af1[ni], Hf, c1, 0, 0, 0);  \
      float p = 0.f;                                                          \
      _Pragma("unroll") for (int i = 0; i < 4; ++i) {                         \
        p = fmaf(fmaxf(c0[i], 0.f), w2a[i], p);                               \
        p = fmaf(fmaxf(c1[i], 0.f), w2b[i], p);                               \
      }                                                                       \
      p += __shfl_xor(p, 16);                                                 \
      p += __shfl_xor(p, 32);                                                 \
      if (lane < 16)                                                          \
        out[(size_t)srow * NN + n] = vld ? (p + sb2v[n]) : 0.0f;              \
    }                                                                         \
  } while (0)

  // Tables/fragments drained; vmem count resets to a clean slate.
  __syncthreads();

  // Prologue: two tiles in flight.
  STAGE(tile0 + 0, buf[0]);
  STAGE(tile0 + 1, buf[1]);
  asm volatile("s_waitcnt vmcnt(6)" ::: "memory");   // tile0 landed (6 newer = tile1)
  __builtin_amdgcn_sched_barrier(0);
  __builtin_amdgcn_s_barrier();

  for (int t = 0; t < TPB - 2; ++t) {
    COMPUTE(t, buf[t % 3]);                // epilogue vmem: 4..6 ops
    STAGE(tile0 + t + 2, buf[(t + 2) % 3]);           // 6 ops
    // Safe lower bound: >= min ops after STAGE(t+1) = 4(epi min) + 6(stage)
    asm volatile("s_waitcnt vmcnt(10)" ::: "memory"); // tile t+1 landed
    __builtin_amdgcn_sched_barrier(0);
    __builtin_amdgcn_s_barrier();
  }

  // t = TPB-2: no further stage; ensure STAGE(TPB-1) landed (>=4 epi ops after)
  COMPUTE(TPB - 2, buf[(TPB - 2) % 3]);
  asm volatile("s_waitcnt vmcnt(4)" ::: "memory");
  __builtin_amdgcn_sched_barrier(0);
  __builtin_amdgcn_s_barrier();
  COMPUTE(TPB - 1, buf[(TPB - 1) % 3]);

#undef STAGE
#undef COMPUTE
}

extern "C" void kernel_launch(void* const* d_in, const int* in_sizes, int n_in,
                              void* d_out, int out_size, void* d_ws, size_t ws_size,
                              hipStream_t stream) {
  const float* h     = (const float*)d_in[0];
  const int*   valid = (const int*)d_in[1];
  const float* W1    = (const float*)d_in[2];
  const float* b1    = (const float*)d_in[3];
  const float* W2    = (const float*)d_in[4];
  const float* b2    = (const float*)d_in[5];
  float* out = (float*)d_out;

  hipLaunchKernelGGL(pack_w1, dim3((NN * 2 * 64 * 8 + 255) / 256), dim3(256),
                     0, stream, W1);
  hipLaunchKernelGGL(mlp_mfma, dim3(NBLK), dim3(512), 0, stream,
                     h, valid, b1, W2, b2, out);
}